// Round 5
// baseline (952.616 us; speedup 1.0000x reference)
//
#include <hip/hip_runtime.h>

// ============================================================================
// Persistent-kernel LSTM decoder, MI355X (gfx950) — round 5.
// vs round 4: (1) deep prefetch ring — gates 5 slots (depth 4), logits 4 slots
// (depth 3): staging becomes issue-bound, not latency-bound; (2) split grid
// barrier: arrive -> prestage next phase's weights (read-only) -> wait, so the
// barrier propagation overlaps weight staging; (3) epoch replicated x8 (one
// line per XCD) to cut same-line poll contention. Coherence model unchanged
// from R4: no agent fences; mutable data via sc0|sc1 (bypass L1/L2, served by
// the memory-side Infinity Cache); weights stay L2-resident.
// ============================================================================

typedef unsigned int uint;
typedef unsigned short ushort;
typedef unsigned long long u64;
typedef __attribute__((ext_vector_type(8))) __bf16 bf16x8;
typedef __attribute__((ext_vector_type(4))) float f32x4;
typedef __attribute__((ext_vector_type(4))) ushort ushort4v;
typedef __attribute__((ext_vector_type(8))) ushort ushort8v;

#define AUXC 0x11  // CPol SC0|SC1: coherent, bypass L1/L2

// ---- workspace byte offsets ----
#define OFF_FLAGS 0L         // 256 x u32 flags; epoch replicas at +1024 (8 x 128B)
#define OFF_W0    4096L      // [32 ng][36 kc] B-frag tiles, 2048x1152 bf16
#define OFF_W1    4722688L   // [32 ng][32 kc], 2048x1024
#define OFF_WO    8916992L   // [80 cg][20 kc], 5120x640 (vocab-padded)
#define OFF_EFT   15470592L  // [40 t][2 mt][16 kc] A-frag, gathered emb
#define OFF_ZFT   25956352L  // [2 mt][4 kc] A-frag of z
#define OFF_TW1   26021888L  // [64 ng][4 kc], 4096x128
#define OFF_TW2   27070464L  // [32 ng][64 kc], 2048x2048
#define OFF_GB    35459072L  // [2 l][2 mt][64 kc] A-frag relu hidden
#define OFF_H0    37556224L  // [2 par][2 mt][16 kc] A-frag h0
#define OFF_H1    38080512L  // [2 par] h1
#define OFF_HS    38604800L  // [2 par] h0+h1 (logits A)
#define OFF_C0    39129088L  // [256][512] f32
#define OFF_C1    39653376L  // [256][512] f32
#define OFF_MB    40177664L  // [2 par][256][40] f32
#define OFF_SB    40259584L  // [2 par][256][40] f32
#define OFF_TGT   40341504L  // [2 par][256] f32

#define HPAR 262144L  // bytes per parity of an A-frag [2mt][16kc] buffer
#define HMT  131072L  // bytes per mt
#define SLOT_G 24576  // gate ring slot: A 16KB | B 8KB   (ring of 5)
#define SLOT_L 32768  // logits ring slot: A 16KB | Blo 8KB | Bhi 8KB (ring of 4)

// ---- relaxed agent-scope (coherence-point) scalar access helpers ----
__device__ __forceinline__ uint ald32(const uint* p) {
  return __hip_atomic_load(p, __ATOMIC_RELAXED, __HIP_MEMORY_SCOPE_AGENT);
}
__device__ __forceinline__ void ast32(uint* p, uint v) {
  __hip_atomic_store(p, v, __ATOMIC_RELAXED, __HIP_MEMORY_SCOPE_AGENT);
}
__device__ __forceinline__ float aldf(const float* p) {
  return __hip_atomic_load(p, __ATOMIC_RELAXED, __HIP_MEMORY_SCOPE_AGENT);
}
__device__ __forceinline__ void astf(float* p, float v) {
  __hip_atomic_store(p, v, __ATOMIC_RELAXED, __HIP_MEMORY_SCOPE_AGENT);
}
__device__ __forceinline__ void ast64(u64* p, u64 v) {
  __hip_atomic_store(p, v, __ATOMIC_RELAXED, __HIP_MEMORY_SCOPE_AGENT);
}

__device__ __forceinline__ ushort f2bf(float f) {
  uint u = __float_as_uint(f);
  u = (u + 0x7fffu + ((u >> 16) & 1u)) >> 16;  // RNE
  return (ushort)u;
}
__device__ __forceinline__ float bf2f(ushort u) { return __uint_as_float(((uint)u) << 16); }
__device__ __forceinline__ float sigm(float v) { return 1.f / (1.f + __expf(-v)); }
__device__ __forceinline__ float tanh_f(float v) {
  float a = fabsf(v);
  float e = __expf(-2.f * a);
  return copysignf((1.f - e) / (1.f + e), v);
}
__device__ __forceinline__ f32x4 mfma16(bf16x8 a, bf16x8 b, f32x4 c) {
  return __builtin_amdgcn_mfma_f32_16x16x32_bf16(a, b, c, 0, 0, 0);
}

// A-fragment-tile element index for a [256 rows][K] matrix, KC = K/32.
__device__ __forceinline__ long fta(int b, int k, int KC) {
  return ((long)(((b >> 7) & 1) * KC + (k >> 5)) << 12) +
         (((((b >> 4) & 7) << 2) + ((k >> 3) & 3)) << 7) + ((b & 15) << 3) + (k & 7);
}

template <int AUX>
__device__ __forceinline__ void gl_lds16(const char* g, char* l) {
  __builtin_amdgcn_global_load_lds((const __attribute__((address_space(1))) void*)g,
                                   (__attribute__((address_space(3))) void*)l, 16, 0, AUX);
}

// ---- staging pieces. Gate section = A 16KB + B 8KB; logits = A 16KB + 2x8KB.
template <int AX0, int AX1, int AX2>
__device__ __forceinline__ void stage_gA(int s, const char* A0, int n0, const char* A1, int n1,
                                         const char* A2, char* dst, int o) {
  if (s < n0) {
    const char* A = A0 + (long)s * 16384;
#pragma unroll
    for (int i = 0; i < 4; ++i) gl_lds16<AX0>(A + i * 4096 + o, dst + i * 4096 + o);
  } else if (s < n0 + n1) {
    const char* A = A1 + (long)(s - n0) * 16384;
#pragma unroll
    for (int i = 0; i < 4; ++i) gl_lds16<AX1>(A + i * 4096 + o, dst + i * 4096 + o);
  } else {
    const char* A = A2 + (long)(s - n0 - n1) * 16384;
#pragma unroll
    for (int i = 0; i < 4; ++i) gl_lds16<AX2>(A + i * 4096 + o, dst + i * 4096 + o);
  }
}
__device__ __forceinline__ void stage_gB(int s, const char* Bs, char* dst, int o) {
  const char* B = Bs + (long)s * 8192;
#pragma unroll
  for (int i = 0; i < 2; ++i) gl_lds16<0>(B + i * 4096 + o, dst + 16384 + i * 4096 + o);
}
template <int AXA>
__device__ __forceinline__ void stage_lA(int s, const char* A0, int n0, const char* A1, char* dst,
                                         int o) {
  const char* A = (s < n0) ? (A0 + (long)s * 16384) : (A1 + (long)(s - n0) * 16384);
  if (s < n0) {
#pragma unroll
    for (int i = 0; i < 4; ++i) gl_lds16<AXA>(A + i * 4096 + o, dst + i * 4096 + o);
  } else {
#pragma unroll
    for (int i = 0; i < 4; ++i) gl_lds16<0>(A + i * 4096 + o, dst + i * 4096 + o);
  }
}
__device__ __forceinline__ void stage_lB(int s, const char* Blo, const char* Bhi, char* dst,
                                         int o) {
  const char* bl = Blo + (long)s * 8192;
  const char* bh = Bhi + (long)s * 8192;
#pragma unroll
  for (int i = 0; i < 2; ++i) gl_lds16<0>(bl + i * 4096 + o, dst + 16384 + i * 4096 + o);
#pragma unroll
  for (int i = 0; i < 2; ++i) gl_lds16<0>(bh + i * 4096 + o, dst + 24576 + i * 4096 + o);
}

// next-phase weight prestage (between arrive and wait)
__device__ __forceinline__ void prestage_gB(const char* Bs, char* smem, int o) {
#pragma unroll
  for (int s = 0; s < 4; ++s) stage_gB(s, Bs, smem + s * SLOT_G, o);
}
__device__ __forceinline__ void prestage_lB(const char* Blo, const char* Bhi, char* smem, int o) {
#pragma unroll
  for (int s = 0; s < 3; ++s) stage_lB(s, Blo, Bhi, smem + s * SLOT_L, o);
}

// vmcnt-only waits. base 0x0F70 (lgkm/exp no-wait); vmcnt hi bits at [15:14].
__device__ __forceinline__ void gwait_split(int s, int rem) {
  if (rem == 0) __builtin_amdgcn_s_waitcnt(0x0F70);       // 0
  else if (rem == 1) __builtin_amdgcn_s_waitcnt(0x0F76);  // 6
  else if (rem == 2) __builtin_amdgcn_s_waitcnt(0x0F7C);  // 12
  else if (s == 0) __builtin_amdgcn_s_waitcnt(0x0F7C);    // 12
  else if (s == 1) __builtin_amdgcn_s_waitcnt(0x0F7E);    // 14
  else if (s == 2) __builtin_amdgcn_s_waitcnt(0x4F70);    // 16
  else __builtin_amdgcn_s_waitcnt(0x4F72);                // 18
}
__device__ __forceinline__ void gwait_plain(int rem) {
  if (rem == 0) __builtin_amdgcn_s_waitcnt(0x0F70);
  else if (rem == 1) __builtin_amdgcn_s_waitcnt(0x0F76);
  else if (rem == 2) __builtin_amdgcn_s_waitcnt(0x0F7C);
  else __builtin_amdgcn_s_waitcnt(0x4F72);
}
__device__ __forceinline__ void lwait_split(int s, int rem) {
  if (rem == 0) __builtin_amdgcn_s_waitcnt(0x0F70);       // 0
  else if (rem == 1) __builtin_amdgcn_s_waitcnt(0x0F78);  // 8
  else if (s == 0) __builtin_amdgcn_s_waitcnt(0x0F78);    // 8
  else if (s == 1) __builtin_amdgcn_s_waitcnt(0x0F7C);    // 12
  else __builtin_amdgcn_s_waitcnt(0x4F70);                // 16
}

__device__ __forceinline__ void gemm_chunk_g(const char* sb, int ab, int bb, f32x4 (&acc)[4][2]) {
#pragma unroll
  for (int c = 0; c < 2; ++c) {
    const char* ap = sb + c * 8192 + ab;
    const char* bp = sb + c * 4096 + bb;
    bf16x8 Af0 = *(const bf16x8*)(ap);
    bf16x8 Af1 = *(const bf16x8*)(ap + 1024);
    bf16x8 Af2 = *(const bf16x8*)(ap + 2048);
    bf16x8 Af3 = *(const bf16x8*)(ap + 3072);
    bf16x8 Bf0 = *(const bf16x8*)(bp);
    bf16x8 Bf1 = *(const bf16x8*)(bp + 1024);
    acc[0][0] = mfma16(Af0, Bf0, acc[0][0]);
    acc[0][1] = mfma16(Af0, Bf1, acc[0][1]);
    acc[1][0] = mfma16(Af1, Bf0, acc[1][0]);
    acc[1][1] = mfma16(Af1, Bf1, acc[1][1]);
    acc[2][0] = mfma16(Af2, Bf0, acc[2][0]);
    acc[2][1] = mfma16(Af2, Bf1, acc[2][1]);
    acc[3][0] = mfma16(Af3, Bf0, acc[3][0]);
    acc[3][1] = mfma16(Af3, Bf1, acc[3][1]);
  }
}

// gates GEMM, B(0..3) already prestaged by caller (split mode).
template <int AX0, int AX1, int AX2>
__device__ __forceinline__ void run_gemm_g5(const char* A0, int n0, const char* A1, int n1,
                                            const char* A2, const char* Bs, int S, char* smem,
                                            int tid, int wm, int wn, int lane,
                                            f32x4 (&acc)[4][2]) {
  const int o = tid * 16;
#pragma unroll
  for (int s = 0; s < 4; ++s) stage_gA<AX0, AX1, AX2>(s, A0, n0, A1, n1, A2, smem + s * SLOT_G, o);
  const int ab = wm * 4096 + lane * 16;
  const int bb = 16384 + wn * 2048 + lane * 16;
  for (int s = 0; s < S; ++s) {
    gwait_split(s, S - 1 - s);
    __builtin_amdgcn_s_barrier();
    char* sb = smem + (s % 5) * SLOT_G;
    if (s + 4 < S) {
      char* d = smem + ((s + 4) % 5) * SLOT_G;
      stage_gA<AX0, AX1, AX2>(s + 4, A0, n0, A1, n1, A2, d, o);
      stage_gB(s + 4, Bs, d, o);
    }
    gemm_chunk_g(sb, ab, bb, acc);
  }
  __syncthreads();
}

// gates GEMM, plain (stages everything itself; used by init phases).
template <int AX0, int AX1, int AX2>
__device__ __forceinline__ void run_gemm_gp(const char* A0, int n0, const char* A1, int n1,
                                            const char* A2, const char* Bs, int S, char* smem,
                                            int tid, int wm, int wn, int lane,
                                            f32x4 (&acc)[4][2]) {
  const int o = tid * 16;
  const int D = S < 4 ? S : 4;
  for (int s = 0; s < D; ++s) {
    char* d = smem + s * SLOT_G;
    stage_gA<AX0, AX1, AX2>(s, A0, n0, A1, n1, A2, d, o);
    stage_gB(s, Bs, d, o);
  }
  const int ab = wm * 4096 + lane * 16;
  const int bb = 16384 + wn * 2048 + lane * 16;
  for (int s = 0; s < S; ++s) {
    gwait_plain(S - 1 - s);
    __builtin_amdgcn_s_barrier();
    char* sb = smem + (s % 5) * SLOT_G;
    if (s + 4 < S) {
      char* d = smem + ((s + 4) % 5) * SLOT_G;
      stage_gA<AX0, AX1, AX2>(s + 4, A0, n0, A1, n1, A2, d, o);
      stage_gB(s + 4, Bs, d, o);
    }
    gemm_chunk_g(sb, ab, bb, acc);
  }
  __syncthreads();
}

// logits 128x128 GEMM, Blo/Bhi(0..2) prestaged by caller.
template <int AXA>
__device__ __forceinline__ void run_gemm_l5(const char* A0, int n0, const char* A1,
                                            const char* Blo, const char* Bhi, int S, char* smem,
                                            int tid, int wm, int wn, int lane,
                                            f32x4 (&acc)[4][4]) {
  const int o = tid * 16;
#pragma unroll
  for (int s = 0; s < 3; ++s) stage_lA<AXA>(s, A0, n0, A1, smem + s * SLOT_L, o);
  const int ab = wm * 4096 + lane * 16;
  const int bb = 16384 + wn * 8192 + lane * 16;
  for (int s = 0; s < S; ++s) {
    lwait_split(s, S - 1 - s);
    __builtin_amdgcn_s_barrier();
    char* sb = smem + (s % 4) * SLOT_L;
    if (s + 3 < S) {
      char* d = smem + ((s + 3) % 4) * SLOT_L;
      stage_lA<AXA>(s + 3, A0, n0, A1, d, o);
      stage_lB(s + 3, Blo, Bhi, d, o);
    }
#pragma unroll
    for (int c = 0; c < 2; ++c) {
      const char* ap = sb + c * 8192 + ab;
      const char* bp = sb + c * 4096 + bb;
      bf16x8 Af[4], Bf[4];
#pragma unroll
      for (int m = 0; m < 4; ++m) Af[m] = *(const bf16x8*)(ap + m * 1024);
#pragma unroll
      for (int n = 0; n < 4; ++n) Bf[n] = *(const bf16x8*)(bp + n * 1024);
#pragma unroll
      for (int m = 0; m < 4; ++m)
#pragma unroll
        for (int n = 0; n < 4; ++n) acc[m][n] = mfma16(Af[m], Bf[n], acc[m][n]);
    }
  }
  __syncthreads();
}

// C/D layout: col = lane&15, row = (lane>>4)*4 + reg
__device__ __forceinline__ void store_lds_tile(float* lds, f32x4 (&acc)[4][2], int wm, int wn,
                                               int lane) {
  const int l15 = lane & 15, lq = lane >> 4;
#pragma unroll
  for (int m = 0; m < 4; ++m)
#pragma unroll
    for (int n = 0; n < 2; ++n)
#pragma unroll
      for (int r = 0; r < 4; ++r)
        lds[(wm * 64 + m * 16 + lq * 4 + r) * 68 + (wn * 32 + n * 16 + l15)] = acc[m][n][r];
}
__device__ __forceinline__ void store_lds_tile128(float* lds, f32x4 (&acc)[4][4], int wm, int wn,
                                                  int lane) {
  const int l15 = lane & 15, lq = lane >> 4;
#pragma unroll
  for (int m = 0; m < 4; ++m)
#pragma unroll
    for (int n = 0; n < 4; ++n)
#pragma unroll
      for (int r = 0; r < 4; ++r)
        lds[(wm * 64 + m * 16 + lq * 4 + r) * 132 + (wn * 64 + n * 16 + l15)] = acc[m][n][r];
}

// split fence-free grid barrier: arrive (flag store) ... wait (epoch poll).
__device__ __forceinline__ void arrive5(uint* flags, uint ph) {
  __syncthreads();  // drains this block's data stores (vmcnt 0) before flag
  if (threadIdx.x == 0) ast32(&flags[blockIdx.x], ph);
}
__device__ __forceinline__ void wait5(uint* flags, uint* epochs, uint ph, bool isAgg, int xcd) {
  if (isAgg) {
    uint v = ald32(&flags[threadIdx.x]);
    while (v < ph) {
      __builtin_amdgcn_s_sleep(1);
      v = ald32(&flags[threadIdx.x]);
    }
    __syncthreads();
    if (threadIdx.x < 8) ast32(&epochs[threadIdx.x * 32], ph);
  } else if (threadIdx.x == 0) {
    uint v = ald32(&epochs[xcd * 32]);
    while (v < ph) {
      __builtin_amdgcn_s_sleep(1);
      v = ald32(&epochs[xcd * 32]);
    }
  }
  __syncthreads();
}

// LSTM gate pointwise; tile [128 b][16 d x 4 g] f32; C in registers.
template <bool WHS>
__device__ __forceinline__ void gates_pw4(const float* tile, int tid, int b0, int d0,
                                          const float* __restrict__ bg, float (&cp)[8],
                                          ushort* __restrict__ hw, const ushort* __restrict__ h0r,
                                          ushort* __restrict__ hs) {
#pragma unroll
  for (int jj = 0; jj < 4; ++jj) {
    const int pi = tid + jj * 256;
    const int bl = pi >> 3, e = pi & 7;
    const f32x4 g0 = ((const f32x4*)tile)[bl * 17 + 2 * e];
    const f32x4 g1 = ((const f32x4*)tile)[bl * 17 + 2 * e + 1];
    const int d = d0 + 2 * e, b = b0 + bl;
    float h2[2];
#pragma unroll
    for (int u = 0; u < 2; ++u) {
      const f32x4 g = u ? g1 : g0;
      const int dd = d + u;
      const float ii = sigm(g[0] + bg[dd]);
      const float ff = sigm(g[1] + bg[512 + dd]);
      const float oo = sigm(g[2] + bg[1024 + dd]);
      const float cn = tanh_f(g[3] + bg[1536 + dd]);
      const float c = ff * cp[jj * 2 + u] + ii * cn;
      cp[jj * 2 + u] = c;
      h2[u] = oo * tanh_f(c);
    }
    const long ft = fta(b, d, 16);
    ast32((uint*)(hw + ft), (uint)f2bf(h2[0]) | ((uint)f2bf(h2[1]) << 16));
    if (WHS) {
      const uint h0p = ald32((const uint*)(h0r + ft));
      const float s0 = h2[0] + bf2f((ushort)(h0p & 0xffffu));
      const float s1 = h2[1] + bf2f((ushort)(h0p >> 16));
      ast32((uint*)(hs + ft), (uint)f2bf(s0) | ((uint)f2bf(s1) << 16));
    }
  }
}

__device__ __forceinline__ float combine_row4(const float* __restrict__ MBc,
                                              const float* __restrict__ SBc,
                                              const float* __restrict__ TGTc, int r, int lane) {
  float M = lane < 40 ? aldf(&MBc[r * 40 + lane]) : -3.0e38f;
  float S = lane < 40 ? aldf(&SBc[r * 40 + lane]) : 0.f;
#pragma unroll
  for (int off = 32; off > 0; off >>= 1) {
    const float Mo = __shfl_xor(M, off, 64);
    const float So = __shfl_xor(S, off, 64);
    const float Mn = fmaxf(M, Mo);
    S = S * __expf(M - Mn) + So * __expf(Mo - Mn);
    M = Mn;
  }
  return aldf(&TGTc[r]) - (M + __logf(S));
}

// ---------------------------------------------------------------------------
__device__ __forceinline__ void cv8(ushort8v& o, const float* s) {
  const f32x4 a = *(const f32x4*)s, b = *(const f32x4*)(s + 4);
#pragma unroll
  for (int j = 0; j < 4; ++j) o[j] = f2bf(a[j]);
#pragma unroll
  for (int j = 0; j < 4; ++j) o[4 + j] = f2bf(b[j]);
}
__device__ __forceinline__ void bft8(ushort* dst, int col, int kg, int KC, const float* src) {
  ushort8v o;
  cv8(o, src);
  *(ushort8v*)(dst + ((long)((col >> 6) * KC + (kg >> 2)) << 11) +
               (((((col >> 4) & 3) << 2) + (kg & 3)) << 7) + ((col & 15) << 3)) = o;
}
__device__ __forceinline__ void bft8z(ushort* dst, int col, int kg, int KC) {
  ushort8v o = (ushort8v)0;
  *(ushort8v*)(dst + ((long)((col >> 6) * KC + (kg >> 2)) << 11) +
               (((((col >> 4) & 3) << 2) + (kg & 3)) << 7) + ((col & 15) << 3)) = o;
}
__device__ __forceinline__ void aft8(ushort* dst, int b, int kg, int KC, const float* src) {
  ushort8v o;
  cv8(o, src);
  *(ushort8v*)(dst + ((long)(((b >> 7) & 1) * KC + (kg >> 2)) << 12) +
               (((((b >> 4) & 7) << 2) + (kg & 3)) << 7) + ((b & 15) << 3)) = o;
}

__global__ void __launch_bounds__(256) prep_kernel(
    const float* __restrict__ Wg0, const float* __restrict__ Wg1, const float* __restrict__ Wout,
    const float* __restrict__ emb, const float* __restrict__ z, const int* __restrict__ x,
    const float* __restrict__ tw1, const float* __restrict__ tw2, unsigned char* __restrict__ ws) {
  ushort* W0 = (ushort*)(ws + OFF_W0);
  ushort* W1 = (ushort*)(ws + OFF_W1);
  ushort* WO = (ushort*)(ws + OFF_WO);
  ushort* EF = (ushort*)(ws + OFF_EFT);
  ushort* ZF = (ushort*)(ws + OFF_ZFT);
  ushort* T1 = (ushort*)(ws + OFF_TW1);
  ushort* T2 = (ushort*)(ws + OFF_TW2);
  const long N0 = 294912, N1 = 262144, N2 = 409600, N3 = 655360, N4 = 4096, N5 = 65536,
             N6 = 524288;
  const long total = N0 + N1 + N2 + N3 + N4 + N5 + N6;
  for (long idx = (long)blockIdx.x * 256 + threadIdx.x; idx < total;
       idx += (long)gridDim.x * 256) {
    long j = idx;
    if (j < N0) {
      const int col = (int)(j / 144), kg = (int)(j - (long)col * 144);
      bft8(W0, col, kg, 36, Wg0 + (long)((col & 3) * 512 + (col >> 2)) * 1152 + kg * 8);
    } else if ((j -= N0) < N1) {
      const int col = (int)(j >> 7), kg = (int)(j & 127);
      bft8(W1, col, kg, 32, Wg1 + (long)((col & 3) * 512 + (col >> 2)) * 1024 + kg * 8);
    } else if ((j -= N1) < N2) {
      const int col = (int)(j / 80), kg = (int)(j - (long)col * 80);
      if (col < 5000)
        bft8(WO, col, kg, 20, Wout + (long)col * 640 + kg * 8);
      else
        bft8z(WO, col, kg, 20);
    } else if ((j -= N2) < N3) {
      const int t = (int)(j >> 14), r = (int)(j & 16383);
      const int b = r >> 6, kg = r & 63;
      aft8(EF + (long)t * 131072, b, kg, 16, emb + (long)x[b * 40 + t] * 512 + kg * 8);
    } else if ((j -= N3) < N4) {
      const int b = (int)(j >> 4), kg = (int)(j & 15);
      aft8(ZF, b, kg, 4, z + b * 128 + kg * 8);
    } else if ((j -= N4) < N5) {
      const int col = (int)(j >> 4), kg = (int)(j & 15);
      bft8(T1, col, kg, 4, tw1 + (long)(col >> 11) * 262144 + (long)(col & 2047) * 128 + kg * 8);
    } else {
      j -= N5;
      const int col = (int)(j >> 8), kg = (int)(j & 255);
      bft8(T2, col, kg, 64, tw2 + (long)(col >> 10) * 2097152 + (long)(col & 1023) * 2048 + kg * 8);
    }
  }
}

// ---------------------------------------------------------------------------
__global__ void __launch_bounds__(256) decoder_main(
    const int* __restrict__ x, const float* __restrict__ bg0, const float* __restrict__ bg1,
    const float* __restrict__ bout, const float* __restrict__ tb1, const float* __restrict__ tb2,
    unsigned char* __restrict__ ws, float* __restrict__ out) {
  __shared__ __align__(16) char smem[131072];  // gates ring 5x24KB; logits 4x32KB

  uint* flags = (uint*)(ws + OFF_FLAGS);
  uint* epochs = (uint*)(ws + OFF_FLAGS + 1024);
  const char* cW0 = (const char*)(ws + OFF_W0);
  const char* cW1 = (const char*)(ws + OFF_W1);
  const char* cWO = (const char*)(ws + OFF_WO);
  const char* cEF = (const char*)(ws + OFF_EFT);
  const char* cZF = (const char*)(ws + OFF_ZFT);
  const char* cT1 = (const char*)(ws + OFF_TW1);
  const char* cT2 = (const char*)(ws + OFF_TW2);
  char* cGB = (char*)(ws + OFF_GB);
  char* cH0 = (char*)(ws + OFF_H0);
  char* cH1 = (char*)(ws + OFF_H1);
  char* cHS = (char*)(ws + OFF_HS);
  float* C0f = (float*)(ws + OFF_C0);
  float* C1f = (float*)(ws + OFF_C1);
  float* MBf = (float*)(ws + OFF_MB);
  float* SBf = (float*)(ws + OFF_SB);
  float* TGTf = (float*)(ws + OFF_TGT);

  const int bid = blockIdx.x;
  const int tid = threadIdx.x;
  const int lane = tid & 63;
  const int w = tid >> 6;
  const int wm = w & 1, wn = w >> 1;
  const int xcd = bid & 7;
  const int slot = bid >> 3;
  const bool isAgg = (bid == 240);
  const int o16 = tid * 16;

  const int mt = slot & 1;
  const int gng = xcd * 4 + ((slot & 7) >> 1);
  const int ls = slot - 16;
  const int lmt = ls & 1;
  const int lng = xcd * 5 + (ls >> 1);

  uint ph = 0;
  float cpriv[8];
  float accO0 = 0.f, accO1 = 0.f;

  // ======== init1: relu(z @ tw1^T + tb1) -> GB ========
  if (slot < 16) {
    const int i_mt = slot & 1, i_ng = xcd * 8 + (slot >> 1);
    f32x4 acc[4][2];
#pragma unroll
    for (int m = 0; m < 4; ++m)
#pragma unroll
      for (int n = 0; n < 2; ++n) acc[m][n] = (f32x4){0.f, 0.f, 0.f, 0.f};
    run_gemm_gp<0, 0, 0>(cZF + (long)i_mt * 32768, 2, nullptr, 0, nullptr,
                         cT1 + (long)i_ng * 16384, 2, smem, tid, wm, wn, lane, acc);
    store_lds_tile((float*)smem, acc, wm, wn, lane);
    __syncthreads();
    const int b0i = i_mt * 128, n0i = i_ng * 64;
    ushort* GBu = (ushort*)cGB;
    for (int i = tid; i < 2048; i += 256) {
      const int bl = i >> 4, q = i & 15;
      const f32x4 v = ((const f32x4*)smem)[bl * 17 + q];
      const int cb = n0i + q * 4;
      const int l = cb >> 11, rr = cb & 2047;
      u64 pk = 0;
#pragma unroll
      for (int cc = 0; cc < 4; ++cc) pk |= (u64)f2bf(fmaxf(v[cc] + tb1[cb + cc], 0.f)) << (cc * 16);
      ast64((u64*)(GBu + (long)l * 524288 + fta(b0i + bl, rr, 64)), pk);
    }
  }
  arrive5(flags, ++ph);
  wait5(flags, epochs, ph, isAgg, xcd);

  // ======== init2: tanh(GB @ tw2^T + tb2) -> (h parity1, C) ========
  if (slot < 8) {
    const int i_mt = slot & 1, i_ng = xcd * 4 + (slot >> 1);
    const int l = i_ng >> 4;
    f32x4 acc[4][2];
#pragma unroll
    for (int m = 0; m < 4; ++m)
#pragma unroll
      for (int n = 0; n < 2; ++n) acc[m][n] = (f32x4){0.f, 0.f, 0.f, 0.f};
    run_gemm_gp<AUXC, 0, 0>(cGB + (long)l * 1048576 + (long)i_mt * 524288, 32, nullptr, 0, nullptr,
                            cT2 + (long)i_ng * 262144, 32, smem, tid, wm, wn, lane, acc);
    store_lds_tile((float*)smem, acc, wm, wn, lane);
    __syncthreads();
    const int b0i = i_mt * 128, n0i = i_ng * 64;
    for (int i = tid; i < 2048; i += 256) {
      const int bl = i >> 4, q = i & 15;
      const f32x4 v = ((const f32x4*)smem)[bl * 17 + q];
      const int cb = n0i + q * 4;
      const int ll = cb >> 10, rr = cb & 1023;
      const int b = b0i + bl;
      if (rr < 512) {
        u64 pk = 0;
#pragma unroll
        for (int cc = 0; cc < 4; ++cc) pk |= (u64)f2bf(tanh_f(v[cc] + tb2[cb + cc])) << (cc * 16);
        ast64((u64*)((ushort*)((ll ? cH1 : cH0) + HPAR) + fta(b, rr, 16)), pk);
      } else {
        float* Cf = (ll ? C1f : C0f) + b * 512 + (rr - 512);
#pragma unroll
        for (int cc = 0; cc < 4; ++cc) astf(Cf + cc, tanh_f(v[cc] + tb2[cb + cc]));
      }
    }
  }
  arrive5(flags, ++ph);
  if (slot < 8) prestage_gB(cW0 + (long)gng * 147456, smem, o16);  // k=0: G0 weights
  __asm__ volatile("" ::: "memory");
  wait5(flags, epochs, ph, isAgg, xcd);

  // C tile -> registers
  if (slot < 16) {
    const float* Cf = (slot < 8) ? C0f : C1f;
#pragma unroll
    for (int jj = 0; jj < 4; ++jj) {
      const int pi = tid + jj * 256, bl = pi >> 3, e = pi & 7;
      const int b = mt * 128 + bl, d = gng * 16 + 2 * e;
      cpriv[jj * 2 + 0] = aldf(&Cf[b * 512 + d]);
      cpriv[jj * 2 + 1] = aldf(&Cf[b * 512 + d + 1]);
    }
  }

  // ======== 42 pipelined phases ========
  for (int k = 0; k < 42; ++k) {
    if (slot < 8) {  // ---- G0: L0 gates, t = k ----
      if (k <= 39) {
        f32x4 acc[4][2];
#pragma unroll
        for (int m = 0; m < 4; ++m)
#pragma unroll
          for (int n = 0; n < 2; ++n) acc[m][n] = (f32x4){0.f, 0.f, 0.f, 0.f};
        run_gemm_g5<AUXC, 0, 0>(cH0 + (long)((k - 1) & 1) * HPAR + (long)mt * HMT, 8,
                                cEF + (long)k * HPAR + (long)mt * HMT, 8, cZF + (long)mt * 32768,
                                cW0 + (long)gng * 147456, 18, smem, tid, wm, wn, lane, acc);
        store_lds_tile((float*)smem, acc, wm, wn, lane);
        __syncthreads();
        gates_pw4<false>((const float*)smem, tid, mt * 128, gng * 16, bg0, cpriv,
                         (ushort*)(cH0 + (long)(k & 1) * HPAR), nullptr, nullptr);
      }
    } else if (slot < 16) {  // ---- G1: L1 gates, t = k-1 (+HS) ----
      if (k >= 1 && k <= 40) {
        f32x4 acc[4][2];
#pragma unroll
        for (int m = 0; m < 4; ++m)
#pragma unroll
          for (int n = 0; n < 2; ++n) acc[m][n] = (f32x4){0.f, 0.f, 0.f, 0.f};
        run_gemm_g5<AUXC, AUXC, 0>(cH1 + (long)(k & 1) * HPAR + (long)mt * HMT, 8,
                                   cH0 + (long)((k - 1) & 1) * HPAR + (long)mt * HMT, 8, nullptr,
                                   cW1 + (long)gng * 131072, 16, smem, tid, wm, wn, lane, acc);
        store_lds_tile((float*)smem, acc, wm, wn, lane);
        __syncthreads();
        gates_pw4<true>((const float*)smem, tid, mt * 128, gng * 16, bg1, cpriv,
                        (ushort*)(cH1 + (long)((k - 1) & 1) * HPAR),
                        (const ushort*)(cH0 + (long)((k - 1) & 1) * HPAR),
                        (ushort*)(cHS + (long)((k - 1) & 1) * HPAR));
      }
    } else if (slot < 26) {  // ---- logits, t' = k-2, target x[.,k-1] ----
      if (k >= 2 && k <= 40) {
        f32x4 acc[4][4];
#pragma unroll
        for (int m = 0; m < 4; ++m)
#pragma unroll
          for (int n = 0; n < 4; ++n) acc[m][n] = (f32x4){0.f, 0.f, 0.f, 0.f};
        run_gemm_l5<AUXC>(cHS + (long)(k & 1) * HPAR + (long)lmt * HMT, 8,
                          cZF + (long)lmt * 32768, cWO + (long)(2 * lng) * 81920,
                          cWO + (long)(2 * lng + 1) * 81920, 10, smem, tid, wm, wn, lane, acc);
        store_lds_tile128((float*)smem, acc, wm, wn, lane);
        __syncthreads();
        const int row = tid >> 1, half = tid & 1, b = lmt * 128 + row;
        const int n0 = lng * 128 + half * 64;
        const int xt = x[b * 40 + (k - 1)];
        const float* rowp = (const float*)smem + row * 132 + half * 64;
        float mx = -3.0e38f, tv = 0.f;
        for (int j = 0; j < 64; j += 4) {
          const f32x4 v = *(const f32x4*)(rowp + j);
#pragma unroll
          for (int cc = 0; cc < 4; ++cc) {
            const int col = n0 + j + cc;
            if (col < 5000) {
              const float val = v[cc] + bout[col];
              mx = fmaxf(mx, val);
              if (col == xt) tv = val;
            }
          }
        }
        float sa = 0.f;
        for (int j = 0; j < 64; j += 4) {
          const f32x4 v = *(const f32x4*)(rowp + j);
#pragma unroll
          for (int cc = 0; cc < 4; ++cc) {
            const int col = n0 + j + cc;
            if (col < 5000) sa += __expf(v[cc] + bout[col] - mx);
          }
        }
        const float mo = __shfl_xor(mx, 1, 64), so = __shfl_xor(sa, 1, 64),
                    to = __shfl_xor(tv, 1, 64);
        const float Mn = fmaxf(mx, mo);
        const float Sm = sa * __expf(mx - Mn) + so * __expf(mo - Mn);
        const int par = k & 1;
        if (half == 0) {
          astf(&MBf[par * 10240 + b * 40 + lng], Mn);
          astf(&SBf[par * 10240 + b * 40 + lng], Sm);
          if (xt >= lng * 128 && xt < lng * 128 + 128) astf(&TGTf[par * 256 + b], tv + to);
        }
      }
    } else if (slot < 30) {  // ---- combine, logits of phase k-1 ----
      if (k >= 3 && k <= 41) {
        const int par = (k - 1) & 1;
        const int r0 = (xcd * 4 + (slot - 26)) * 8 + w * 2;
        accO0 += combine_row4(MBf + par * 10240, SBf + par * 10240, TGTf + par * 256, r0, lane);
        accO1 +=
            combine_row4(MBf + par * 10240, SBf + par * 10240, TGTf + par * 256, r0 + 1, lane);
      }
    }

    // ---- phase boundary: arrive -> prestage next weights -> wait ----
    arrive5(flags, ++ph);
    const int kn = k + 1;
    if (kn < 42) {
      if (slot < 8) {
        if (kn <= 39) prestage_gB(cW0 + (long)gng * 147456, smem, o16);
      } else if (slot < 16) {
        if (kn >= 1 && kn <= 40) prestage_gB(cW1 + (long)gng * 131072, smem, o16);
      } else if (slot < 26) {
        if (kn >= 2 && kn <= 40)
          prestage_lB(cWO + (long)(2 * lng) * 81920, cWO + (long)(2 * lng + 1) * 81920, smem, o16);
      }
    }
    __asm__ volatile("" ::: "memory");
    wait5(flags, epochs, ph, isAgg, xcd);
  }

  if (slot >= 26 && slot < 30 && lane == 0) {
    const int r0 = (xcd * 4 + (slot - 26)) * 8 + w * 2;
    out[r0] = accO0;
    out[r0 + 1] = accO1;
  }
}

// ---------------------------------------------------------------------------
extern "C" void kernel_launch(void* const* d_in, const int* in_sizes, int n_in, void* d_out,
                              int out_size, void* d_ws, size_t ws_size, hipStream_t stream) {
  const float* z = (const float*)d_in[0];
  const int* x = (const int*)d_in[1];
  const float* emb = (const float*)d_in[2];
  const float* Wg0 = (const float*)d_in[3];
  const float* bg0 = (const float*)d_in[4];
  const float* Wg1 = (const float*)d_in[5];
  const float* bg1 = (const float*)d_in[6];
  const float* Wout = (const float*)d_in[7];
  const float* bout = (const float*)d_in[8];
  const float* tw1 = (const float*)d_in[9];
  const float* tb1 = (const float*)d_in[10];
  const float* tw2 = (const float*)d_in[11];
  const float* tb2 = (const float*)d_in[12];
  unsigned char* ws = (unsigned char*)d_ws;
  float* out = (float*)d_out;

  hipMemsetAsync(ws, 0, 4096, stream);  // flags + epoch replicas
  prep_kernel<<<2048, 256, 0, stream>>>(Wg0, Wg1, Wout, emb, z, x, tw1, tw2, ws);
  decoder_main<<<256, 256, 0, stream>>>(x, bg0, bg1, bout, tb1, tb2, ws, out);
}

// Round 6
// 896.962 us; speedup vs baseline: 1.0620x; 1.0620x over previous
//
#include <hip/hip_runtime.h>

// ============================================================================
// Persistent-kernel LSTM decoder, MI355X (gfx950) — round 6.
// vs round 5: NO global barrier at all. Pure dataflow: per-buffer monotonic
// ready counters (relaxed agent atomics at the coherence point). Producers
// signal after __syncthreads drains their sc0|sc1 stores; consumers spin
// (1 thread) then issue control-dependent coherent staging. All inter-step
// buffers are 4-deep (t%4) with loose anti-dependency polls 3 steps back, so
// roles decouple and stalls absorb into slack instead of convoying.
// K-sections reordered so independent operands (emb/z/weights) prestage
// BEFORE the poll; only h-dependent sections stage after detection.
// ============================================================================

typedef unsigned int uint;
typedef unsigned short ushort;
typedef unsigned long long u64;
typedef __attribute__((ext_vector_type(8))) __bf16 bf16x8;
typedef __attribute__((ext_vector_type(4))) float f32x4;
typedef __attribute__((ext_vector_type(4))) ushort ushort4v;
typedef __attribute__((ext_vector_type(8))) ushort ushort8v;

#define AUXC 0x11  // CPol SC0|SC1: coherent, bypass L1/L2

// ---- workspace byte offsets ----
#define OFF_CNT 0L           // ready counters, one per 256B line
#define OFF_W0  4096L        // [32 ng][36 kc] B-frag, 2048x1152 bf16
#define OFF_W1  4722688L     // [32 ng][32 kc], 2048x1024
#define OFF_WO  8916992L     // [80 cg][20 kc], 5120x640 (vocab-padded)
#define OFF_EFT 15470592L    // [40 t][2 mt][16 kc] A-frag gathered emb
#define OFF_ZFT 25956352L    // [2 mt][4 kc] A-frag z
#define OFF_TW1 26021888L    // [64 ng][4 kc], 4096x128
#define OFF_TW2 27070464L    // [32 ng][64 kc], 2048x2048
#define OFF_GB  35459072L    // [2 l][2 mt][64 kc] A-frag relu hidden
#define OFF_H0  37556224L    // [4 slot][2 mt][16 kc] A-frag h0
#define OFF_H1  38604800L    // [4 slot] h1
#define OFF_HS  39653376L    // [4 slot] h0+h1
#define OFF_C0  40701952L    // [256][512] f32
#define OFF_C1  41226240L    // [256][512] f32
#define OFF_MB  41750528L    // [4 slot][256][40] f32
#define OFF_SB  41914368L    // [4 slot][256][40] f32
#define OFF_TGT 42078208L    // [4 slot][256] f32

#define HPAR 262144L  // bytes per slot of an A-frag [2mt][16kc] buffer
#define HMT  131072L  // bytes per mt
#define SLOT_G 24576  // gate ring slot: A 16KB | B 8KB   (ring of 5)
#define SLOT_L 32768  // logits ring slot: A 16KB | Blo 8KB | Bhi 8KB (ring of 4)

// ---- relaxed agent-scope (coherence-point) access helpers ----
__device__ __forceinline__ uint ald32(const uint* p) {
  return __hip_atomic_load(p, __ATOMIC_RELAXED, __HIP_MEMORY_SCOPE_AGENT);
}
__device__ __forceinline__ void ast32(uint* p, uint v) {
  __hip_atomic_store(p, v, __ATOMIC_RELAXED, __HIP_MEMORY_SCOPE_AGENT);
}
__device__ __forceinline__ float aldf(const float* p) {
  return __hip_atomic_load(p, __ATOMIC_RELAXED, __HIP_MEMORY_SCOPE_AGENT);
}
__device__ __forceinline__ void astf(float* p, float v) {
  __hip_atomic_store(p, v, __ATOMIC_RELAXED, __HIP_MEMORY_SCOPE_AGENT);
}
__device__ __forceinline__ void ast64(u64* p, u64 v) {
  __hip_atomic_store(p, v, __ATOMIC_RELAXED, __HIP_MEMORY_SCOPE_AGENT);
}

// producer signal: drain all waves' stores, then one relaxed fetch_add.
__device__ __forceinline__ void signal(uint* c) {
  __syncthreads();
  if (threadIdx.x == 0)
    __hip_atomic_fetch_add(c, 1u, __ATOMIC_RELAXED, __HIP_MEMORY_SCOPE_AGENT);
}
// consumer wait: 1 poller, sleep backoff; subsequent loads are
// control-dependent on the observed value (causally ordered).
__device__ __forceinline__ void waitcnt_ge(const uint* c, uint tgt) {
  if (threadIdx.x == 0) {
    while (ald32(c) < tgt) __builtin_amdgcn_s_sleep(1);
  }
  __syncthreads();
}

__device__ __forceinline__ ushort f2bf(float f) {
  uint u = __float_as_uint(f);
  u = (u + 0x7fffu + ((u >> 16) & 1u)) >> 16;  // RNE
  return (ushort)u;
}
__device__ __forceinline__ float bf2f(ushort u) { return __uint_as_float(((uint)u) << 16); }
__device__ __forceinline__ float sigm(float v) { return 1.f / (1.f + __expf(-v)); }
__device__ __forceinline__ float tanh_f(float v) {
  float a = fabsf(v);
  float e = __expf(-2.f * a);
  return copysignf((1.f - e) / (1.f + e), v);
}
__device__ __forceinline__ f32x4 mfma16(bf16x8 a, bf16x8 b, f32x4 c) {
  return __builtin_amdgcn_mfma_f32_16x16x32_bf16(a, b, c, 0, 0, 0);
}

// A-fragment-tile element index for a [256 rows][K] matrix, KC = K/32.
__device__ __forceinline__ long fta(int b, int k, int KC) {
  return ((long)(((b >> 7) & 1) * KC + (k >> 5)) << 12) +
         (((((b >> 4) & 7) << 2) + ((k >> 3) & 3)) << 7) + ((b & 15) << 3) + (k & 7);
}

template <int AUX>
__device__ __forceinline__ void gl_lds16(const char* g, char* l) {
  __builtin_amdgcn_global_load_lds((const __attribute__((address_space(1))) void*)g,
                                   (__attribute__((address_space(3))) void*)l, 16, 0, AUX);
}

// stage one 16KB A-section (4 loads/thread)
template <int AX>
__device__ __forceinline__ void stageA4(const char* A, char* dst, int o) {
#pragma unroll
  for (int i = 0; i < 4; ++i) gl_lds16<AX>(A + i * 4096 + o, dst + i * 4096 + o);
}
// stage one 8KB gate B-section (2 loads/thread), explicit B-section index
__device__ __forceinline__ void stage_gB(int bsec, const char* Bs, char* dst, int o) {
  const char* B = Bs + (long)bsec * 8192;
#pragma unroll
  for (int i = 0; i < 2; ++i) gl_lds16<0>(B + i * 4096 + o, dst + 16384 + i * 4096 + o);
}
// stage logits B pair (4 loads/thread)
__device__ __forceinline__ void stage_lB(int bsec, const char* Blo, const char* Bhi, char* dst,
                                         int o) {
  const char* bl = Blo + (long)bsec * 8192;
  const char* bh = Bhi + (long)bsec * 8192;
#pragma unroll
  for (int i = 0; i < 2; ++i) gl_lds16<0>(bl + i * 4096 + o, dst + 16384 + i * 4096 + o);
#pragma unroll
  for (int i = 0; i < 2; ++i) gl_lds16<0>(bh + i * 4096 + o, dst + 24576 + i * 4096 + o);
}

// ring vmcnt waits (6-load gate sections, depth 4): wait for oldest section
__device__ __forceinline__ void gw3(int r) {
  if (r <= 0) __builtin_amdgcn_s_waitcnt(0x0F70);       // vmcnt 0
  else if (r == 1) __builtin_amdgcn_s_waitcnt(0x0F76);  // 6
  else if (r == 2) __builtin_amdgcn_s_waitcnt(0x0F7C);  // 12
  else __builtin_amdgcn_s_waitcnt(0x4F72);              // 18
}
// logits (8-load sections, depth 3)
__device__ __forceinline__ void lw2(int r) {
  if (r <= 0) __builtin_amdgcn_s_waitcnt(0x0F70);       // 0
  else if (r == 1) __builtin_amdgcn_s_waitcnt(0x0F78);  // 8
  else __builtin_amdgcn_s_waitcnt(0x4F70);              // 16
}

__device__ __forceinline__ void gemm_chunk_g(const char* sb, int ab, int bb, f32x4 (&acc)[4][2]) {
#pragma unroll
  for (int c = 0; c < 2; ++c) {
    const char* ap = sb + c * 8192 + ab;
    const char* bp = sb + c * 4096 + bb;
    bf16x8 Af0 = *(const bf16x8*)(ap);
    bf16x8 Af1 = *(const bf16x8*)(ap + 1024);
    bf16x8 Af2 = *(const bf16x8*)(ap + 2048);
    bf16x8 Af3 = *(const bf16x8*)(ap + 3072);
    bf16x8 Bf0 = *(const bf16x8*)(bp);
    bf16x8 Bf1 = *(const bf16x8*)(bp + 1024);
    acc[0][0] = mfma16(Af0, Bf0, acc[0][0]);
    acc[0][1] = mfma16(Af0, Bf1, acc[0][1]);
    acc[1][0] = mfma16(Af1, Bf0, acc[1][0]);
    acc[1][1] = mfma16(Af1, Bf1, acc[1][1]);
    acc[2][0] = mfma16(Af2, Bf0, acc[2][0]);
    acc[2][1] = mfma16(Af2, Bf1, acc[2][1]);
    acc[3][0] = mfma16(Af3, Bf0, acc[3][0]);
    acc[3][1] = mfma16(Af3, Bf1, acc[3][1]);
  }
}

// ---- init-phase plain ring GEMM (natural K order, B sec = s) ----
template <int AXA>
__device__ __forceinline__ void run_gemm_init(const char* A0, const char* Bs, int S, char* smem,
                                              int tid, int wm, int wn, int lane,
                                              f32x4 (&acc)[4][2]) {
  const int o = tid * 16;
  const int D = S < 4 ? S : 4;
  for (int s = 0; s < D; ++s) {
    char* d = smem + s * SLOT_G;
    stageA4<AXA>(A0 + (long)s * 16384, d, o);
    stage_gB(s, Bs, d, o);
  }
  const int ab = wm * 4096 + lane * 16;
  const int bb = 16384 + wn * 2048 + lane * 16;
  for (int s = 0; s < S; ++s) {
    const int rem = S - 1 - s;
    gw3(rem < 3 ? rem : 3);
    __builtin_amdgcn_s_barrier();
    char* sb = smem + (s % 5) * SLOT_G;
    if (s + 4 < S) {
      char* d = smem + ((s + 4) % 5) * SLOT_G;
      stageA4<AXA>(A0 + (long)(s + 4) * 16384, d, o);
      stage_gB(s + 4, Bs, d, o);
    }
    gemm_chunk_g(sb, ab, bb, acc);
  }
  __syncthreads();
}

// C/D layout: col = lane&15, row = (lane>>4)*4 + reg
__device__ __forceinline__ void store_lds_tile(float* lds, f32x4 (&acc)[4][2], int wm, int wn,
                                               int lane) {
  const int l15 = lane & 15, lq = lane >> 4;
#pragma unroll
  for (int m = 0; m < 4; ++m)
#pragma unroll
    for (int n = 0; n < 2; ++n)
#pragma unroll
      for (int r = 0; r < 4; ++r)
        lds[(wm * 64 + m * 16 + lq * 4 + r) * 68 + (wn * 32 + n * 16 + l15)] = acc[m][n][r];
}
__device__ __forceinline__ void store_lds_tile128(float* lds, f32x4 (&acc)[4][4], int wm, int wn,
                                                  int lane) {
  const int l15 = lane & 15, lq = lane >> 4;
#pragma unroll
  for (int m = 0; m < 4; ++m)
#pragma unroll
    for (int n = 0; n < 4; ++n)
#pragma unroll
      for (int r = 0; r < 4; ++r)
        lds[(wm * 64 + m * 16 + lq * 4 + r) * 132 + (wn * 64 + n * 16 + l15)] = acc[m][n][r];
}

// LSTM gate pointwise; tile [128 b][16 d x 4 g] f32; C in registers.
template <bool WHS>
__device__ __forceinline__ void gates_pw4(const float* tile, int tid, int b0, int d0,
                                          const float* __restrict__ bg, float (&cp)[8],
                                          ushort* __restrict__ hw, const ushort* __restrict__ h0r,
                                          ushort* __restrict__ hs) {
#pragma unroll
  for (int jj = 0; jj < 4; ++jj) {
    const int pi = tid + jj * 256;
    const int bl = pi >> 3, e = pi & 7;
    const f32x4 g0 = ((const f32x4*)tile)[bl * 17 + 2 * e];
    const f32x4 g1 = ((const f32x4*)tile)[bl * 17 + 2 * e + 1];
    const int d = d0 + 2 * e, b = b0 + bl;
    float h2[2];
#pragma unroll
    for (int u = 0; u < 2; ++u) {
      const f32x4 g = u ? g1 : g0;
      const int dd = d + u;
      const float ii = sigm(g[0] + bg[dd]);
      const float ff = sigm(g[1] + bg[512 + dd]);
      const float oo = sigm(g[2] + bg[1024 + dd]);
      const float cn = tanh_f(g[3] + bg[1536 + dd]);
      const float c = ff * cp[jj * 2 + u] + ii * cn;
      cp[jj * 2 + u] = c;
      h2[u] = oo * tanh_f(c);
    }
    const long ft = fta(b, d, 16);
    ast32((uint*)(hw + ft), (uint)f2bf(h2[0]) | ((uint)f2bf(h2[1]) << 16));
    if (WHS) {
      const uint h0p = ald32((const uint*)(h0r + ft));
      const float s0 = h2[0] + bf2f((ushort)(h0p & 0xffffu));
      const float s1 = h2[1] + bf2f((ushort)(h0p >> 16));
      ast32((uint*)(hs + ft), (uint)f2bf(s0) | ((uint)f2bf(s1) << 16));
    }
  }
}

__device__ __forceinline__ float combine_row4(const float* __restrict__ MBc,
                                              const float* __restrict__ SBc,
                                              const float* __restrict__ TGTc, int r, int lane) {
  float M = lane < 40 ? aldf(&MBc[r * 40 + lane]) : -3.0e38f;
  float S = lane < 40 ? aldf(&SBc[r * 40 + lane]) : 0.f;
#pragma unroll
  for (int off = 32; off > 0; off >>= 1) {
    const float Mo = __shfl_xor(M, off, 64);
    const float So = __shfl_xor(S, off, 64);
    const float Mn = fmaxf(M, Mo);
    S = S * __expf(M - Mn) + So * __expf(Mo - Mn);
    M = Mn;
  }
  return aldf(&TGTc[r]) - (M + __logf(S));
}

// ---------------------------------------------------------------------------
__device__ __forceinline__ void cv8(ushort8v& o, const float* s) {
  const f32x4 a = *(const f32x4*)s, b = *(const f32x4*)(s + 4);
#pragma unroll
  for (int j = 0; j < 4; ++j) o[j] = f2bf(a[j]);
#pragma unroll
  for (int j = 0; j < 4; ++j) o[4 + j] = f2bf(b[j]);
}
__device__ __forceinline__ void bft8(ushort* dst, int col, int kg, int KC, const float* src) {
  ushort8v o;
  cv8(o, src);
  *(ushort8v*)(dst + ((long)((col >> 6) * KC + (kg >> 2)) << 11) +
               (((((col >> 4) & 3) << 2) + (kg & 3)) << 7) + ((col & 15) << 3)) = o;
}
__device__ __forceinline__ void bft8z(ushort* dst, int col, int kg, int KC) {
  ushort8v o = (ushort8v)0;
  *(ushort8v*)(dst + ((long)((col >> 6) * KC + (kg >> 2)) << 11) +
               (((((col >> 4) & 3) << 2) + (kg & 3)) << 7) + ((col & 15) << 3)) = o;
}
__device__ __forceinline__ void aft8(ushort* dst, int b, int kg, int KC, const float* src) {
  ushort8v o;
  cv8(o, src);
  *(ushort8v*)(dst + ((long)(((b >> 7) & 1) * KC + (kg >> 2)) << 12) +
               (((((b >> 4) & 7) << 2) + (kg & 3)) << 7) + ((b & 15) << 3)) = o;
}

__global__ void __launch_bounds__(256) prep_kernel(
    const float* __restrict__ Wg0, const float* __restrict__ Wg1, const float* __restrict__ Wout,
    const float* __restrict__ emb, const float* __restrict__ z, const int* __restrict__ x,
    const float* __restrict__ tw1, const float* __restrict__ tw2, unsigned char* __restrict__ ws) {
  ushort* W0 = (ushort*)(ws + OFF_W0);
  ushort* W1 = (ushort*)(ws + OFF_W1);
  ushort* WO = (ushort*)(ws + OFF_WO);
  ushort* EF = (ushort*)(ws + OFF_EFT);
  ushort* ZF = (ushort*)(ws + OFF_ZFT);
  ushort* T1 = (ushort*)(ws + OFF_TW1);
  ushort* T2 = (ushort*)(ws + OFF_TW2);
  const long N0 = 294912, N1 = 262144, N2 = 409600, N3 = 655360, N4 = 4096, N5 = 65536,
             N6 = 524288;
  const long total = N0 + N1 + N2 + N3 + N4 + N5 + N6;
  for (long idx = (long)blockIdx.x * 256 + threadIdx.x; idx < total;
       idx += (long)gridDim.x * 256) {
    long j = idx;
    if (j < N0) {
      const int col = (int)(j / 144), kg = (int)(j - (long)col * 144);
      bft8(W0, col, kg, 36, Wg0 + (long)((col & 3) * 512 + (col >> 2)) * 1152 + kg * 8);
    } else if ((j -= N0) < N1) {
      const int col = (int)(j >> 7), kg = (int)(j & 127);
      bft8(W1, col, kg, 32, Wg1 + (long)((col & 3) * 512 + (col >> 2)) * 1024 + kg * 8);
    } else if ((j -= N1) < N2) {
      const int col = (int)(j / 80), kg = (int)(j - (long)col * 80);
      if (col < 5000)
        bft8(WO, col, kg, 20, Wout + (long)col * 640 + kg * 8);
      else
        bft8z(WO, col, kg, 20);
    } else if ((j -= N2) < N3) {
      const int t = (int)(j >> 14), r = (int)(j & 16383);
      const int b = r >> 6, kg = r & 63;
      aft8(EF + (long)t * 131072, b, kg, 16, emb + (long)x[b * 40 + t] * 512 + kg * 8);
    } else if ((j -= N3) < N4) {
      const int b = (int)(j >> 4), kg = (int)(j & 15);
      aft8(ZF, b, kg, 4, z + b * 128 + kg * 8);
    } else if ((j -= N4) < N5) {
      const int col = (int)(j >> 4), kg = (int)(j & 15);
      bft8(T1, col, kg, 4, tw1 + (long)(col >> 11) * 262144 + (long)(col & 2047) * 128 + kg * 8);
    } else {
      j -= N5;
      const int col = (int)(j >> 8), kg = (int)(j & 255);
      bft8(T2, col, kg, 64, tw2 + (long)(col >> 10) * 2097152 + (long)(col & 1023) * 2048 + kg * 8);
    }
  }
}

// ---------------------------------------------------------------------------
__global__ void __launch_bounds__(256) decoder_main(
    const int* __restrict__ x, const float* __restrict__ bg0, const float* __restrict__ bg1,
    const float* __restrict__ bout, const float* __restrict__ tb1, const float* __restrict__ tb2,
    unsigned char* __restrict__ ws, float* __restrict__ out) {
  __shared__ __align__(16) char smem[131072];

  uint* CNT = (uint*)(ws + OFF_CNT);
  uint* C_I1 = CNT + 0;    // init1 done (target 128)
  uint* C_I2 = CNT + 64;   // init2 done (target 64)
  uint* C_H0 = CNT + 128;  // h0 instances (64/instance)
  uint* C_H1 = CNT + 192;  // h1+HS instances (64/instance)
  uint* C_LG = CNT + 256;  // logits instances (80/instance)
  uint* C_CB = CNT + 320;  // combine instances (32/instance)

  const char* cW0 = (const char*)(ws + OFF_W0);
  const char* cW1 = (const char*)(ws + OFF_W1);
  const char* cWO = (const char*)(ws + OFF_WO);
  const char* cEF = (const char*)(ws + OFF_EFT);
  const char* cZF = (const char*)(ws + OFF_ZFT);
  const char* cT1 = (const char*)(ws + OFF_TW1);
  const char* cT2 = (const char*)(ws + OFF_TW2);
  char* cGB = (char*)(ws + OFF_GB);
  char* cH0 = (char*)(ws + OFF_H0);
  char* cH1 = (char*)(ws + OFF_H1);
  char* cHS = (char*)(ws + OFF_HS);
  float* C0f = (float*)(ws + OFF_C0);
  float* C1f = (float*)(ws + OFF_C1);
  float* MBf = (float*)(ws + OFF_MB);
  float* SBf = (float*)(ws + OFF_SB);
  float* TGTf = (float*)(ws + OFF_TGT);

  const int bid = blockIdx.x;
  const int tid = threadIdx.x;
  const int lane = tid & 63;
  const int w = tid >> 6;
  const int wm = w & 1, wn = w >> 1;
  const int xcd = bid & 7;
  const int slot = bid >> 3;
  const int o16 = tid * 16;
  if (slot >= 30) return;  // 16 idle blocks

  const int ab = wm * 4096 + lane * 16;
  const int bbg = 16384 + wn * 2048 + lane * 16;
  const int bbl = 16384 + wn * 8192 + lane * 16;

  float cpriv[8];
  float accO0 = 0.f, accO1 = 0.f;

  // ======== init1 (128 blocks): relu(z @ tw1^T + tb1) -> GB ========
  if (slot < 16) {
    const int i_mt = slot & 1, i_ng = xcd * 8 + (slot >> 1);
    f32x4 acc[4][2];
#pragma unroll
    for (int m = 0; m < 4; ++m)
#pragma unroll
      for (int n = 0; n < 2; ++n) acc[m][n] = (f32x4){0.f, 0.f, 0.f, 0.f};
    run_gemm_init<0>(cZF + (long)i_mt * 32768, cT1 + (long)i_ng * 16384, 2, smem, tid, wm, wn,
                     lane, acc);
    store_lds_tile((float*)smem, acc, wm, wn, lane);
    __syncthreads();
    const int b0i = i_mt * 128, n0i = i_ng * 64;
    ushort* GBu = (ushort*)cGB;
    for (int i = tid; i < 2048; i += 256) {
      const int bl = i >> 4, q = i & 15;
      const f32x4 v = ((const f32x4*)smem)[bl * 17 + q];
      const int cb = n0i + q * 4;
      const int l = cb >> 11, rr = cb & 2047;
      u64 pk = 0;
#pragma unroll
      for (int cc = 0; cc < 4; ++cc) pk |= (u64)f2bf(fmaxf(v[cc] + tb1[cb + cc], 0.f)) << (cc * 16);
      ast64((u64*)(GBu + (long)l * 524288 + fta(b0i + bl, rr, 64)), pk);
    }
    signal(C_I1);
  }

  // ======== init2 (64 blocks): tanh(GB @ tw2^T + tb2) -> (h slot3, C) ========
  if (slot < 8) {
    waitcnt_ge(C_I1, 128u);
    const int i_mt = slot & 1, i_ng = xcd * 4 + (slot >> 1);
    const int l = i_ng >> 4;
    f32x4 acc[4][2];
#pragma unroll
    for (int m = 0; m < 4; ++m)
#pragma unroll
      for (int n = 0; n < 2; ++n) acc[m][n] = (f32x4){0.f, 0.f, 0.f, 0.f};
    run_gemm_init<AUXC>(cGB + (long)l * 1048576 + (long)i_mt * 524288,
                        cT2 + (long)i_ng * 262144, 32, smem, tid, wm, wn, lane, acc);
    store_lds_tile((float*)smem, acc, wm, wn, lane);
    __syncthreads();
    const int b0i = i_mt * 128, n0i = i_ng * 64;
    for (int i = tid; i < 2048; i += 256) {
      const int bl = i >> 4, q = i & 15;
      const f32x4 v = ((const f32x4*)smem)[bl * 17 + q];
      const int cb = n0i + q * 4;
      const int ll = cb >> 10, rr = cb & 1023;
      const int b = b0i + bl;
      if (rr < 512) {  // initial h -> slot 3
        u64 pk = 0;
#pragma unroll
        for (int cc = 0; cc < 4; ++cc) pk |= (u64)f2bf(tanh_f(v[cc] + tb2[cb + cc])) << (cc * 16);
        ast64((u64*)((ushort*)((ll ? cH1 : cH0) + 3L * HPAR) + fta(b, rr, 16)), pk);
      } else {
        float* Cf = (ll ? C1f : C0f) + b * 512 + (rr - 512);
#pragma unroll
        for (int cc = 0; cc < 4; ++cc) astf(Cf + cc, tanh_f(v[cc] + tb2[cb + cc]));
      }
    }
    signal(C_I2);
  }

  // ======== role loops (39 steps: t = 0..38) ========
  if (slot < 8) {
    // ---------------- G0: L0 gates ----------------
    const int mt = slot & 1, gng = xcd * 4 + (slot >> 1);
    const char* Az = cZF + (long)mt * 32768;
    const char* Bs = cW0 + (long)gng * 147456;
    waitcnt_ge(C_I2, 64u);
#pragma unroll
    for (int jj = 0; jj < 4; ++jj) {
      const int pi = tid + jj * 256, bl = pi >> 3, e = pi & 7;
      cpriv[jj * 2 + 0] = aldf(&C0f[(mt * 128 + bl) * 512 + gng * 16 + 2 * e]);
      cpriv[jj * 2 + 1] = aldf(&C0f[(mt * 128 + bl) * 512 + gng * 16 + 2 * e + 1]);
    }
    for (int t = 0; t < 39; ++t) {
      const char* Ah = cH0 + (long)((t + 3) & 3) * HPAR + (long)mt * HMT;
      const char* Ae = cEF + (long)t * HPAR + (long)mt * HMT;
      // prestage ring pos 0..3 = emb sections (independent) before polling
#pragma unroll
      for (int p = 0; p < 4; ++p) {
        char* d = smem + p * SLOT_G;
        stageA4<0>(Ae + (long)p * 16384, d, o16);
        stage_gB(p + 8, Bs, d, o16);
      }
      if (t >= 1) waitcnt_ge(C_H0, 64u * (uint)t);
      if (t >= 4) waitcnt_ge(C_H1, 64u * (uint)(t - 3));
      f32x4 acc[4][2];
#pragma unroll
      for (int m = 0; m < 4; ++m)
#pragma unroll
        for (int n = 0; n < 2; ++n) acc[m][n] = (f32x4){0.f, 0.f, 0.f, 0.f};
      for (int s = 0; s < 18; ++s) {
        const int rem = 17 - s;
        gw3(rem < 3 ? rem : 3);
        __builtin_amdgcn_s_barrier();
        char* sb = smem + (s % 5) * SLOT_G;
        const int sn = s + 4;
        if (sn < 18) {
          char* d = smem + (sn % 5) * SLOT_G;
          if (sn < 8) stageA4<0>(Ae + (long)sn * 16384, d, o16);
          else if (sn < 10) stageA4<0>(Az + (long)(sn - 8) * 16384, d, o16);
          else stageA4<AUXC>(Ah + (long)(sn - 10) * 16384, d, o16);
          stage_gB(sn < 10 ? sn + 8 : sn - 10, Bs, d, o16);
        }
        gemm_chunk_g(sb, ab, bbg, acc);
      }
      __syncthreads();
      store_lds_tile((float*)smem, acc, wm, wn, lane);
      __syncthreads();
      gates_pw4<false>((const float*)smem, tid, mt * 128, gng * 16, bg0, cpriv,
                       (ushort*)(cH0 + (long)(t & 3) * HPAR), nullptr, nullptr);
      signal(C_H0);
    }
  } else if (slot < 16) {
    // ---------------- G1: L1 gates (+HS) ----------------
    const int mt = slot & 1, gng = xcd * 4 + ((slot & 7) >> 1);
    const char* Bs = cW1 + (long)gng * 131072;
    waitcnt_ge(C_I2, 64u);
#pragma unroll
    for (int jj = 0; jj < 4; ++jj) {
      const int pi = tid + jj * 256, bl = pi >> 3, e = pi & 7;
      cpriv[jj * 2 + 0] = aldf(&C1f[(mt * 128 + bl) * 512 + gng * 16 + 2 * e]);
      cpriv[jj * 2 + 1] = aldf(&C1f[(mt * 128 + bl) * 512 + gng * 16 + 2 * e + 1]);
    }
    for (int t = 0; t < 39; ++t) {
      const char* Ah1 = cH1 + (long)((t + 3) & 3) * HPAR + (long)mt * HMT;
      const char* Ah0 = cH0 + (long)(t & 3) * HPAR + (long)mt * HMT;
      if (t >= 1) waitcnt_ge(C_H1, 64u * (uint)t);  // h1(t-1) ready
      // prestage ring pos 0..3 = h1 sections (now safe) before the h0 poll
#pragma unroll
      for (int p = 0; p < 4; ++p) {
        char* d = smem + p * SLOT_G;
        stageA4<AUXC>(Ah1 + (long)p * 16384, d, o16);
        stage_gB(p, Bs, d, o16);
      }
      waitcnt_ge(C_H0, 64u * (uint)(t + 1));             // h0(t) ready
      if (t >= 4) waitcnt_ge(C_LG, 80u * (uint)(t - 3)); // HS slot free
      f32x4 acc[4][2];
#pragma unroll
      for (int m = 0; m < 4; ++m)
#pragma unroll
        for (int n = 0; n < 2; ++n) acc[m][n] = (f32x4){0.f, 0.f, 0.f, 0.f};
      for (int s = 0; s < 16; ++s) {
        const int rem = 15 - s;
        gw3(rem < 3 ? rem : 3);
        __builtin_amdgcn_s_barrier();
        char* sb = smem + (s % 5) * SLOT_G;
        const int sn = s + 4;
        if (sn < 16) {
          char* d = smem + (sn % 5) * SLOT_G;
          if (sn < 8) stageA4<AUXC>(Ah1 + (long)sn * 16384, d, o16);
          else stageA4<AUXC>(Ah0 + (long)(sn - 8) * 16384, d, o16);
          stage_gB(sn, Bs, d, o16);
        }
        gemm_chunk_g(sb, ab, bbg, acc);
      }
      __syncthreads();
      store_lds_tile((float*)smem, acc, wm, wn, lane);
      __syncthreads();
      gates_pw4<true>((const float*)smem, tid, mt * 128, gng * 16, bg1, cpriv,
                      (ushort*)(cH1 + (long)(t & 3) * HPAR),
                      (const ushort*)(cH0 + (long)(t & 3) * HPAR),
                      (ushort*)(cHS + (long)(t & 3) * HPAR));
      signal(C_H1);
    }
  } else if (slot < 26) {
    // ---------------- logits ----------------
    const int ls = slot - 16, lmt = ls & 1, lng = xcd * 5 + (ls >> 1);
    const char* Blo = cWO + (long)(2 * lng) * 81920;
    const char* Bhi = cWO + (long)(2 * lng + 1) * 81920;
    const char* Az = cZF + (long)lmt * 32768;
    for (int t = 0; t < 39; ++t) {
      const char* Ahs = cHS + (long)(t & 3) * HPAR + (long)lmt * HMT;
      waitcnt_ge(C_H1, 64u * (uint)(t + 1));             // HS(t) ready
      if (t >= 4) waitcnt_ge(C_CB, 32u * (uint)(t - 3)); // MB slot free
      // prestage ring pos 0..2: z,z,HS(0)
#pragma unroll
      for (int p = 0; p < 3; ++p) {
        char* d = smem + p * SLOT_L;
        if (p < 2) stageA4<0>(Az + (long)p * 16384, d, o16);
        else stageA4<AUXC>(Ahs, d, o16);
        stage_lB(p < 2 ? p + 8 : p - 2, Blo, Bhi, d, o16);
      }
      f32x4 acc[4][4];
#pragma unroll
      for (int m = 0; m < 4; ++m)
#pragma unroll
        for (int n = 0; n < 4; ++n) acc[m][n] = (f32x4){0.f, 0.f, 0.f, 0.f};
      for (int s = 0; s < 10; ++s) {
        const int rem = 9 - s;
        lw2(rem < 2 ? rem : 2);
        __builtin_amdgcn_s_barrier();
        char* sb = smem + (s % 4) * SLOT_L;
        const int sn = s + 3;
        if (sn < 10) {
          char* d = smem + (sn % 4) * SLOT_L;
          stageA4<AUXC>(Ahs + (long)(sn - 2) * 16384, d, o16);
          stage_lB(sn - 2, Blo, Bhi, d, o16);
        }
#pragma unroll
        for (int c = 0; c < 2; ++c) {
          const char* ap = sb + c * 8192 + ab;
          const char* bp = sb + c * 4096 + bbl;
          bf16x8 Af[4], Bf[4];
#pragma unroll
          for (int m = 0; m < 4; ++m) Af[m] = *(const bf16x8*)(ap + m * 1024);
#pragma unroll
          for (int n = 0; n < 4; ++n) Bf[n] = *(const bf16x8*)(bp + n * 1024);
#pragma unroll
          for (int m = 0; m < 4; ++m)
#pragma unroll
            for (int n = 0; n < 4; ++n) acc[m][n] = mfma16(Af[m], Bf[n], acc[m][n]);
        }
      }
      __syncthreads();
      store_lds_tile128((float*)smem, acc, wm, wn, lane);
      __syncthreads();
      const int row = tid >> 1, half = tid & 1, b = lmt * 128 + row;
      const int n0 = lng * 128 + half * 64;
      const int xt = x[b * 40 + t + 1];
      const float* rowp = (const float*)smem + row * 132 + half * 64;
      float mx = -3.0e38f, tv = 0.f;
      for (int j = 0; j < 64; j += 4) {
        const f32x4 v = *(const f32x4*)(rowp + j);
#pragma unroll
        for (int cc = 0; cc < 4; ++cc) {
          const int col = n0 + j + cc;
          if (col < 5000) {
            const float val = v[cc] + bout[col];
            mx = fmaxf(mx, val);
            if (col == xt) tv = val;
          }
        }
      }
      float sa = 0.f;
      for (int j = 0; j < 64; j += 4) {
        const f32x4 v = *(const f32x4*)(rowp + j);
#pragma unroll
        for (int cc = 0; cc < 4; ++cc) {
          const int col = n0 + j + cc;
          if (col < 5000) sa += __expf(v[cc] + bout[col] - mx);
        }
      }
      const float mo = __shfl_xor(mx, 1, 64), so = __shfl_xor(sa, 1, 64),
                  to = __shfl_xor(tv, 1, 64);
      const float Mn = fmaxf(mx, mo);
      const float Sm = sa * __expf(mx - Mn) + so * __expf(mo - Mn);
      const int sl = t & 3;
      if (half == 0) {
        astf(&MBf[sl * 10240 + b * 40 + lng], Mn);
        astf(&SBf[sl * 10240 + b * 40 + lng], Sm);
        if (xt >= lng * 128 && xt < lng * 128 + 128) astf(&TGTf[sl * 256 + b], tv + to);
      }
      signal(C_LG);
    }
  } else {
    // ---------------- combine ----------------
    const int r0 = (xcd * 4 + (slot - 26)) * 8 + w * 2;
    for (int t = 0; t < 39; ++t) {
      waitcnt_ge(C_LG, 80u * (uint)(t + 1));
      const int sl = t & 3;
      accO0 += combine_row4(MBf + sl * 10240, SBf + sl * 10240, TGTf + sl * 256, r0, lane);
      accO1 += combine_row4(MBf + sl * 10240, SBf + sl * 10240, TGTf + sl * 256, r0 + 1, lane);
      signal(C_CB);
    }
    if (lane == 0) {
      out[r0] = accO0;
      out[r0 + 1] = accO1;
    }
  }
}

// ---------------------------------------------------------------------------
extern "C" void kernel_launch(void* const* d_in, const int* in_sizes, int n_in, void* d_out,
                              int out_size, void* d_ws, size_t ws_size, hipStream_t stream) {
  const float* z = (const float*)d_in[0];
  const int* x = (const int*)d_in[1];
  const float* emb = (const float*)d_in[2];
  const float* Wg0 = (const float*)d_in[3];
  const float* bg0 = (const float*)d_in[4];
  const float* Wg1 = (const float*)d_in[5];
  const float* bg1 = (const float*)d_in[6];
  const float* Wout = (const float*)d_in[7];
  const float* bout = (const float*)d_in[8];
  const float* tw1 = (const float*)d_in[9];
  const float* tb1 = (const float*)d_in[10];
  const float* tw2 = (const float*)d_in[11];
  const float* tb2 = (const float*)d_in[12];
  unsigned char* ws = (unsigned char*)d_ws;
  float* out = (float*)d_out;

  hipMemsetAsync(ws, 0, 4096, stream);  // ready counters
  prep_kernel<<<2048, 256, 0, stream>>>(Wg0, Wg1, Wout, emb, z, x, tw1, tw2, ws);
  decoder_main<<<256, 256, 0, stream>>>(x, bg0, bg1, bout, tb1, tb2, ws, out);
}